// Round 1
// 1040.169 us; speedup vs baseline: 1.0261x; 1.0261x over previous
//
#include <hip/hip_runtime.h>
#include <hip/hip_bf16.h>
#include <math.h>

// Problem constants
#define B_TOT 4096
#define NN 512
#define MM 64
#define HID 256
#define COUT 128
#define PSZ 70              // PARAM_SIZE = M + 1 + 1 + 3 + 1
#define REPRN 268           // 2*PSZ + 2*M
#define IN_SZ 73            // SEQ_W+1 + M
#define WS_STRIDE 352       // floats per batch element in workspace
#define BT 8                // batch rows per block in controller kernel

// Workspace layout per b (floats), stride WS_STRIDE:
//   [0:128)   ctrl_out
//   [128:192) kt_read (tanh'd key)
//   [192:256) kt_write
//   [256:320) ae = a - e
//   [320] knorm_r [321] beta_r [322] g_r [323..325] sm_r [326] gamma_r
//   [328] knorm_w [329] beta_w [330] g_w [331..333] sm_w [334] gamma_w

__device__ __forceinline__ float sigmoidf_(float v){ return 1.f/(1.f+expf(-v)); }
__device__ __forceinline__ float softplusf_(float v){ return v > 20.f ? v : log1pf(expf(v)); }
__device__ __forceinline__ float leakyf_(float v){ return v >= 0.f ? v : 0.01f*v; }

__device__ __forceinline__ float wave_sum(float v){
  #pragma unroll
  for (int o = 32; o; o >>= 1) v += __shfl_xor(v, o);
  return v;
}
__device__ __forceinline__ float wave_max(float v){
  #pragma unroll
  for (int o = 32; o; o >>= 1) v = fmaxf(v, __shfl_xor(v, o));
  return v;
}

// 8-wave (512-thread) block reductions
__device__ float block_sum8(float v, float* red){
  v = wave_sum(v);
  int w = threadIdx.x >> 6, l = threadIdx.x & 63;
  __syncthreads();               // protect red from previous use
  if (l == 0) red[w] = v;
  __syncthreads();
  float s = 0.f;
  #pragma unroll
  for (int i = 0; i < 8; ++i) s += red[i];
  return s;
}
__device__ float block_max8(float v, float* red){
  v = wave_max(v);
  int w = threadIdx.x >> 6, l = threadIdx.x & 63;
  __syncthreads();
  if (l == 0) red[w] = v;
  __syncthreads();
  float m = red[0];
  #pragma unroll
  for (int i = 1; i < 8; ++i) m = fmaxf(m, red[i]);
  return m;
}

// ---------------- Kernel 1: controller MLP + parameter transforms ----------
__global__ __launch_bounds__(256) void k_ctrl(
    const float* __restrict__ x, const float* __restrict__ prev_read,
    const float* __restrict__ W0, const float* __restrict__ b0,
    const float* __restrict__ W1, const float* __restrict__ b1,
    const float* __restrict__ Wout, const float* __restrict__ bout,
    const float* __restrict__ rW, const float* __restrict__ rb,
    float* __restrict__ pws)
{
  __shared__ float cin[BT][80];
  __shared__ float sA[BT][256];
  __shared__ float sB[BT][256];
  __shared__ float sR[BT][272];
  const int t = threadIdx.x;
  const int bbase = blockIdx.x * BT;

  // load controller inputs: concat(x[9], prev_read[64])
  for (int idx = t; idx < BT * IN_SZ; idx += 256){
    int bb = idx / IN_SZ, i = idx - bb * IN_SZ;
    int b = bbase + bb;
    cin[bb][i] = (i < 9) ? x[b * 9 + i] : prev_read[b * MM + (i - 9)];
  }
  __syncthreads();

  // h0 = leaky(cin @ W0 + b0), W0 is [73,256] row-major
  {
    float acc[BT];
    #pragma unroll
    for (int bb = 0; bb < BT; ++bb) acc[bb] = 0.f;
    for (int i = 0; i < IN_SZ; ++i){
      float w = W0[i * 256 + t];
      #pragma unroll
      for (int bb = 0; bb < BT; ++bb) acc[bb] += cin[bb][i] * w;
    }
    float bias = b0[t];
    #pragma unroll
    for (int bb = 0; bb < BT; ++bb) sA[bb][t] = leakyf_(acc[bb] + bias);
  }
  __syncthreads();

  // h1 = leaky(h0 @ W1 + b1), W1 [256,256]
  {
    float acc[BT];
    #pragma unroll
    for (int bb = 0; bb < BT; ++bb) acc[bb] = 0.f;
    for (int i = 0; i < 256; ++i){
      float w = W1[i * 256 + t];
      #pragma unroll
      for (int bb = 0; bb < BT; ++bb) acc[bb] += sA[bb][i] * w;
    }
    float bias = b1[t];
    #pragma unroll
    for (int bb = 0; bb < BT; ++bb) sB[bb][t] = leakyf_(acc[bb] + bias);
  }
  __syncthreads();

  // ctrl_out = tanh(h1 @ Wout + bout), Wout [256,128] ; store into sA[...][0..127] and ws
  if (t < COUT){
    float acc[BT];
    #pragma unroll
    for (int bb = 0; bb < BT; ++bb) acc[bb] = 0.f;
    for (int i = 0; i < 256; ++i){
      float w = Wout[i * COUT + t];
      #pragma unroll
      for (int bb = 0; bb < BT; ++bb) acc[bb] += sB[bb][i] * w;
    }
    float bias = bout[t];
    #pragma unroll
    for (int bb = 0; bb < BT; ++bb){
      float v = tanhf(acc[bb] + bias);
      sA[bb][t] = v;
      pws[(size_t)(bbase + bb) * WS_STRIDE + t] = v;
    }
  }
  __syncthreads();

  // reprx = ctrl_out @ rW + rb, rW [128,268]; thread does cols t and t+256
  {
    float acc1[BT], acc2[BT];
    #pragma unroll
    for (int bb = 0; bb < BT; ++bb){ acc1[bb] = 0.f; acc2[bb] = 0.f; }
    const bool has2 = (t + 256) < REPRN;
    for (int i = 0; i < COUT; ++i){
      float w1 = rW[i * REPRN + t];
      float w2 = has2 ? rW[i * REPRN + t + 256] : 0.f;
      #pragma unroll
      for (int bb = 0; bb < BT; ++bb){
        float c = sA[bb][i];
        acc1[bb] += c * w1;
        acc2[bb] += c * w2;
      }
    }
    float r1 = rb[t];
    float r2 = has2 ? rb[t + 256] : 0.f;
    #pragma unroll
    for (int bb = 0; bb < BT; ++bb){
      sR[bb][t] = acc1[bb] + r1;
      if (has2) sR[bb][t + 256] = acc2[bb] + r2;
    }
  }
  __syncthreads();

  // derived params per b
  for (int bb = 0; bb < BT; ++bb){
    float* pb = pws + (size_t)(bbase + bb) * WS_STRIDE;
    if (t < 64){                          // wave 0: read key
      float kt = tanhf(sR[bb][t]);
      pb[128 + t] = kt;
      float s = wave_sum(kt * kt);
      if (t == 0) pb[320] = sqrtf(s);
    } else if (t < 128){                  // wave 1: write key
      int m = t - 64;
      float kt = tanhf(sR[bb][PSZ + m]);
      pb[192 + m] = kt;
      float s = wave_sum(kt * kt);
      if (m == 0) pb[328] = sqrtf(s);
    } else if (t < 192){                  // wave 2: e, a -> a - e
      int m = t - 128;
      float e = sigmoidf_(sR[bb][2 * PSZ + m]);
      float a = tanhf(sR[bb][2 * PSZ + MM + m]);
      pb[256 + m] = a - e;
    } else if (t == 192 || t == 193){     // scalars for each head
      int off = (t == 192) ? 0 : PSZ;
      int po  = (t == 192) ? 320 : 328;
      float beta = sR[bb][off + 64];
      float g    = sR[bb][off + 65];
      float s0 = sR[bb][off + 66], s1 = sR[bb][off + 67], s2 = sR[bb][off + 68];
      float gm = sR[bb][off + 69];
      pb[po + 1] = softplusf_(beta);
      pb[po + 2] = sigmoidf_(g);
      float mx = fmaxf(s0, fmaxf(s1, s2));
      float e0 = expf(s0 - mx), e1 = expf(s1 - mx), e2 = expf(s2 - mx);
      float inv = 1.f / (e0 + e1 + e2);
      pb[po + 3] = e0 * inv; pb[po + 4] = e1 * inv; pb[po + 5] = e2 * inv;
      pb[po + 6] = softplusf_(gm) + 1.f;
    }
  }
}

// --------- addressing helper: softmax -> gate -> shift -> sharpen ----------
// 512 threads, one memory row per thread.
__device__ void address_head(const float* __restrict__ dot, const float* __restrict__ ssv,
                             float knorm, float beta, float g,
                             float sm0, float sm1, float sm2, float gamma,
                             const float* __restrict__ wprev,
                             float* tmp, float* wfin, float* red)
{
  const int t = threadIdx.x;
  float c = dot[t] / fmaxf(sqrtf(ssv[t]) * knorm, 1e-8f);
  float v = beta * c;
  float vmax = block_max8(v, red);
  float e = expf(v - vmax);
  float S = block_sum8(e, red);
  float wg = g * (e / S) + (1.f - g) * wprev[t];
  tmp[t] = wg;
  __syncthreads();
  // circular shift: ws[i] = wg[i-1]*sm0 + wg[i]*sm1 + wg[i+1]*sm2
  float ws = tmp[(t + 511) & 511] * sm0 + wg * sm1 + tmp[(t + 1) & 511] * sm2;
  float p = powf(ws, gamma);
  float S2 = block_sum8(p, red);
  wfin[t] = p / S2;
  __syncthreads();
}

// ---------------- Kernel 2: addressing + read + bank update + seq_out -----
// 512 threads per block, one b per block. The 128 KB bank slice is loaded
// ONCE into registers (16 x float4 per thread = 64 VGPRs) and reused for
// the read-vector + new_bank pass, removing the second 512 MB HBM read.
__global__ __launch_bounds__(512, 2) void k_head(
    const float* __restrict__ bank,
    const float* __restrict__ w_read, const float* __restrict__ w_write,
    const float* __restrict__ outW, const float* __restrict__ outb,
    const float* __restrict__ pws,
    float* __restrict__ out)   // [B*8 seq_out][B*N*M new_bank]
{
  __shared__ float dotr[512], dotw[512], ssv[512], tmp[512], wfr[512], wfw[512];
  __shared__ float red[8];
  __shared__ float readpart[8][64];
  __shared__ float readv[64];

  const int b = blockIdx.x;
  const int t = threadIdx.x;
  const int lane = t & 63, wave = t >> 6;
  const int mg = lane & 15;        // m-group: covers m = mg*4 .. mg*4+3
  const int rsub = lane >> 4;      // row-sub within wave (0..3)

  const float* bankB = bank + (size_t)b * (NN * MM);
  const float* pb = pws + (size_t)b * WS_STRIDE;

  const float4 ktr = *(const float4*)(pb + 128 + mg * 4);
  const float4 ktw = *(const float4*)(pb + 192 + mg * 4);

  // ---- pass A: load bank slice into registers (coalesced: each wave covers
  //      4 consecutive rows = 1 KB contiguous per instruction) ----
  float4 bank_r[16];
  #pragma unroll
  for (int it = 0; it < 16; ++it){
    int n = it * 32 + wave * 4 + rsub;
    bank_r[it] = *(const float4*)(bankB + n * MM + mg * 4);
  }

  // dot products with both keys + row sum-of-squares (16-lane reduce)
  #pragma unroll
  for (int it = 0; it < 16; ++it){
    float4 p = bank_r[it];
    float dr = p.x * ktr.x + p.y * ktr.y + p.z * ktr.z + p.w * ktr.w;
    float dw = p.x * ktw.x + p.y * ktw.y + p.z * ktw.z + p.w * ktw.w;
    float sq = p.x * p.x + p.y * p.y + p.z * p.z + p.w * p.w;
    #pragma unroll
    for (int msk = 1; msk < 16; msk <<= 1){
      dr += __shfl_xor(dr, msk);
      dw += __shfl_xor(dw, msk);
      sq += __shfl_xor(sq, msk);
    }
    if (mg == 0){
      int n = it * 32 + wave * 4 + rsub;
      dotr[n] = dr; dotw[n] = dw; ssv[n] = sq;
    }
  }
  __syncthreads();

  // ---- phase B: addressing for read and write heads ----
  address_head(dotr, ssv, pb[320], pb[321], pb[322], pb[323], pb[324], pb[325], pb[326],
               w_read + (size_t)b * NN, tmp, wfr, red);
  address_head(dotw, ssv, pb[328], pb[329], pb[330], pb[331], pb[332], pb[333], pb[334],
               w_write + (size_t)b * NN, tmp, wfw, red);

  // ---- pass C: read vector + new_bank write, from registers ----
  const float4 ae4 = *(const float4*)(pb + 256 + mg * 4);
  float* outBank = out + (size_t)B_TOT * 8 + (size_t)b * (NN * MM);
  float4 racc = make_float4(0.f, 0.f, 0.f, 0.f);
  #pragma unroll
  for (int it = 0; it < 16; ++it){
    int n = it * 32 + wave * 4 + rsub;
    float4 p = bank_r[it];
    float wr = wfr[n], wwn = wfw[n];
    float4 q;
    q.x = p.x + wwn * ae4.x; q.y = p.y + wwn * ae4.y;
    q.z = p.z + wwn * ae4.z; q.w = p.w + wwn * ae4.w;
    *(float4*)(outBank + n * MM + mg * 4) = q;
    racc.x += wr * p.x; racc.y += wr * p.y; racc.z += wr * p.z; racc.w += wr * p.w;
  }
  // reduce read accumulator over rows (lanes sharing mg differ in bits 4,5)
  racc.x += __shfl_xor(racc.x, 16); racc.x += __shfl_xor(racc.x, 32);
  racc.y += __shfl_xor(racc.y, 16); racc.y += __shfl_xor(racc.y, 32);
  racc.z += __shfl_xor(racc.z, 16); racc.z += __shfl_xor(racc.z, 32);
  racc.w += __shfl_xor(racc.w, 16); racc.w += __shfl_xor(racc.w, 32);
  if (lane < 16){
    readpart[wave][mg * 4 + 0] = racc.x;
    readpart[wave][mg * 4 + 1] = racc.y;
    readpart[wave][mg * 4 + 2] = racc.z;
    readpart[wave][mg * 4 + 3] = racc.w;
  }
  __syncthreads();
  if (t < 64){
    float s = 0.f;
    #pragma unroll
    for (int w = 0; w < 8; ++w) s += readpart[w][t];
    readv[t] = s;
  }
  __syncthreads();

  // ---- seq_out: sigmoid([ctrl_out, read] @ outW + outb), wave-parallel ----
  if (t < 64){
    int j = t >> 3, s = t & 7;       // output j, partial-slice s
    float acc = 0.f;
    for (int i = s; i < COUT; i += 8) acc += pb[i] * outW[i * 8 + j];
    for (int m = s; m < MM; m += 8)   acc += readv[m] * outW[(COUT + m) * 8 + j];
    acc += __shfl_xor(acc, 1);
    acc += __shfl_xor(acc, 2);
    acc += __shfl_xor(acc, 4);
    if (s == 0) out[(size_t)b * 8 + j] = sigmoidf_(acc + outb[j]);
  }
}

extern "C" void kernel_launch(void* const* d_in, const int* in_sizes, int n_in,
                              void* d_out, int out_size, void* d_ws, size_t ws_size,
                              hipStream_t stream) {
  const float* x         = (const float*)d_in[0];
  const float* prev_read = (const float*)d_in[1];
  const float* bank      = (const float*)d_in[2];
  const float* w_read    = (const float*)d_in[3];
  const float* w_write   = (const float*)d_in[4];
  const float* W0        = (const float*)d_in[5];
  const float* b0        = (const float*)d_in[6];
  const float* W1        = (const float*)d_in[7];
  const float* b1        = (const float*)d_in[8];
  const float* Wout      = (const float*)d_in[9];
  const float* bout      = (const float*)d_in[10];
  const float* rW        = (const float*)d_in[11];
  const float* rb        = (const float*)d_in[12];
  const float* outW      = (const float*)d_in[13];
  const float* outb      = (const float*)d_in[14];
  float* out = (float*)d_out;
  float* pws = (float*)d_ws;   // needs 4096*352*4 = 5.77 MB

  k_ctrl<<<dim3(B_TOT / BT), dim3(256), 0, stream>>>(
      x, prev_read, W0, b0, W1, b1, Wout, bout, rW, rb, pws);
  k_head<<<dim3(B_TOT), dim3(512), 0, stream>>>(
      bank, w_read, w_write, outW, outb, pws, out);
}

// Round 2
// 973.120 us; speedup vs baseline: 1.0968x; 1.0689x over previous
//
#include <hip/hip_runtime.h>
#include <hip/hip_bf16.h>
#include <math.h>

// Problem constants
#define B_TOT 4096
#define NN 512
#define MM 64
#define HID 256
#define COUT 128
#define PSZ 70              // PARAM_SIZE = M + 1 + 1 + 3 + 1
#define REPRN 268           // 2*PSZ + 2*M
#define IN_SZ 73            // SEQ_W+1 + M
#define WS_STRIDE 352       // floats per batch element in workspace
#define BT 8                // batch rows per block in controller kernel
#define CTS 12              // transposed activation stride (12 floats: 16B-aligned rows, conflict-spread stores)

// Workspace layout per b (floats), stride WS_STRIDE:
//   [0:128)   ctrl_out
//   [128:192) kt_read (tanh'd key)
//   [192:256) kt_write
//   [256:320) ae = a - e
//   [320] knorm_r [321] beta_r [322] g_r [323..325] sm_r [326] gamma_r
//   [328] knorm_w [329] beta_w [330] g_w [331..333] sm_w [334] gamma_w

__device__ __forceinline__ float sigmoidf_(float v){ return 1.f/(1.f+expf(-v)); }
__device__ __forceinline__ float softplusf_(float v){ return v > 20.f ? v : log1pf(expf(v)); }
__device__ __forceinline__ float leakyf_(float v){ return v >= 0.f ? v : 0.01f*v; }

__device__ __forceinline__ float wave_sum(float v){
  #pragma unroll
  for (int o = 32; o; o >>= 1) v += __shfl_xor(v, o);
  return v;
}

// ---------------- Kernel 1: controller MLP + parameter transforms ----------
// Activations stored TRANSPOSED [neuron][bb] so the 8 per-batch values are
// read as 2 x float4 uniform LDS reads instead of 8 scalar broadcasts
// (4x fewer DS instructions; k_ctrl is LDS-issue-bound).
__global__ __launch_bounds__(256) void k_ctrl(
    const float* __restrict__ x, const float* __restrict__ prev_read,
    const float* __restrict__ W0, const float* __restrict__ b0,
    const float* __restrict__ W1, const float* __restrict__ b1,
    const float* __restrict__ Wout, const float* __restrict__ bout,
    const float* __restrict__ rW, const float* __restrict__ rb,
    float* __restrict__ pws)
{
  __shared__ float cinT[80][CTS];    // [i][bb]
  __shared__ float hAT[256][CTS];
  __shared__ float hBT[256][CTS];
  __shared__ float coT[128][CTS];
  __shared__ float sR[BT][272];
  const int t = threadIdx.x;
  const int bbase = blockIdx.x * BT;

  // load controller inputs: concat(x[9], prev_read[64]) -> transposed
  for (int idx = t; idx < BT * IN_SZ; idx += 256){
    int bb = idx / IN_SZ, i = idx - bb * IN_SZ;
    int b = bbase + bb;
    cinT[i][bb] = (i < 9) ? x[b * 9 + i] : prev_read[b * MM + (i - 9)];
  }
  __syncthreads();

  // h0 = leaky(cin @ W0 + b0), W0 is [73,256] row-major
  {
    float4 acA = make_float4(0.f,0.f,0.f,0.f), acB = make_float4(0.f,0.f,0.f,0.f);
    for (int i = 0; i < IN_SZ; ++i){
      float w = W0[i * 256 + t];
      float4 a0 = *(const float4*)&cinT[i][0];
      float4 a1 = *(const float4*)&cinT[i][4];
      acA.x += a0.x * w; acA.y += a0.y * w; acA.z += a0.z * w; acA.w += a0.w * w;
      acB.x += a1.x * w; acB.y += a1.y * w; acB.z += a1.z * w; acB.w += a1.w * w;
    }
    float bias = b0[t];
    acA.x = leakyf_(acA.x + bias); acA.y = leakyf_(acA.y + bias);
    acA.z = leakyf_(acA.z + bias); acA.w = leakyf_(acA.w + bias);
    acB.x = leakyf_(acB.x + bias); acB.y = leakyf_(acB.y + bias);
    acB.z = leakyf_(acB.z + bias); acB.w = leakyf_(acB.w + bias);
    *(float4*)&hAT[t][0] = acA;
    *(float4*)&hAT[t][4] = acB;
  }
  __syncthreads();

  // h1 = leaky(h0 @ W1 + b1), W1 [256,256]
  {
    float4 acA = make_float4(0.f,0.f,0.f,0.f), acB = make_float4(0.f,0.f,0.f,0.f);
    for (int i = 0; i < 256; ++i){
      float w = W1[i * 256 + t];
      float4 a0 = *(const float4*)&hAT[i][0];
      float4 a1 = *(const float4*)&hAT[i][4];
      acA.x += a0.x * w; acA.y += a0.y * w; acA.z += a0.z * w; acA.w += a0.w * w;
      acB.x += a1.x * w; acB.y += a1.y * w; acB.z += a1.z * w; acB.w += a1.w * w;
    }
    float bias = b1[t];
    acA.x = leakyf_(acA.x + bias); acA.y = leakyf_(acA.y + bias);
    acA.z = leakyf_(acA.z + bias); acA.w = leakyf_(acA.w + bias);
    acB.x = leakyf_(acB.x + bias); acB.y = leakyf_(acB.y + bias);
    acB.z = leakyf_(acB.z + bias); acB.w = leakyf_(acB.w + bias);
    *(float4*)&hBT[t][0] = acA;
    *(float4*)&hBT[t][4] = acB;
  }
  __syncthreads();

  // ctrl_out = tanh(h1 @ Wout + bout), Wout [256,128]
  if (t < COUT){
    float4 acA = make_float4(0.f,0.f,0.f,0.f), acB = make_float4(0.f,0.f,0.f,0.f);
    for (int i = 0; i < 256; ++i){
      float w = Wout[i * COUT + t];
      float4 a0 = *(const float4*)&hBT[i][0];
      float4 a1 = *(const float4*)&hBT[i][4];
      acA.x += a0.x * w; acA.y += a0.y * w; acA.z += a0.z * w; acA.w += a0.w * w;
      acB.x += a1.x * w; acB.y += a1.y * w; acB.z += a1.z * w; acB.w += a1.w * w;
    }
    float bias = bout[t];
    acA.x = tanhf(acA.x + bias); acA.y = tanhf(acA.y + bias);
    acA.z = tanhf(acA.z + bias); acA.w = tanhf(acA.w + bias);
    acB.x = tanhf(acB.x + bias); acB.y = tanhf(acB.y + bias);
    acB.z = tanhf(acB.z + bias); acB.w = tanhf(acB.w + bias);
    *(float4*)&coT[t][0] = acA;
    *(float4*)&coT[t][4] = acB;
    pws[(size_t)(bbase + 0) * WS_STRIDE + t] = acA.x;
    pws[(size_t)(bbase + 1) * WS_STRIDE + t] = acA.y;
    pws[(size_t)(bbase + 2) * WS_STRIDE + t] = acA.z;
    pws[(size_t)(bbase + 3) * WS_STRIDE + t] = acA.w;
    pws[(size_t)(bbase + 4) * WS_STRIDE + t] = acB.x;
    pws[(size_t)(bbase + 5) * WS_STRIDE + t] = acB.y;
    pws[(size_t)(bbase + 6) * WS_STRIDE + t] = acB.z;
    pws[(size_t)(bbase + 7) * WS_STRIDE + t] = acB.w;
  }
  __syncthreads();

  // reprx = ctrl_out @ rW + rb, rW [128,268]; thread does cols t and t+256 (t<12)
  {
    float4 a1A = make_float4(0.f,0.f,0.f,0.f), a1B = make_float4(0.f,0.f,0.f,0.f);
    float4 a2A = make_float4(0.f,0.f,0.f,0.f), a2B = make_float4(0.f,0.f,0.f,0.f);
    const bool has2 = (t + 256) < REPRN;
    for (int i = 0; i < COUT; ++i){
      float w1 = rW[i * REPRN + t];
      float w2 = has2 ? rW[i * REPRN + t + 256] : 0.f;
      float4 c0 = *(const float4*)&coT[i][0];
      float4 c1 = *(const float4*)&coT[i][4];
      a1A.x += c0.x * w1; a1A.y += c0.y * w1; a1A.z += c0.z * w1; a1A.w += c0.w * w1;
      a1B.x += c1.x * w1; a1B.y += c1.y * w1; a1B.z += c1.z * w1; a1B.w += c1.w * w1;
      a2A.x += c0.x * w2; a2A.y += c0.y * w2; a2A.z += c0.z * w2; a2A.w += c0.w * w2;
      a2B.x += c1.x * w2; a2B.y += c1.y * w2; a2B.z += c1.z * w2; a2B.w += c1.w * w2;
    }
    float r1 = rb[t];
    float r2 = has2 ? rb[t + 256] : 0.f;
    sR[0][t] = a1A.x + r1; sR[1][t] = a1A.y + r1;
    sR[2][t] = a1A.z + r1; sR[3][t] = a1A.w + r1;
    sR[4][t] = a1B.x + r1; sR[5][t] = a1B.y + r1;
    sR[6][t] = a1B.z + r1; sR[7][t] = a1B.w + r1;
    if (has2){
      sR[0][t+256] = a2A.x + r2; sR[1][t+256] = a2A.y + r2;
      sR[2][t+256] = a2A.z + r2; sR[3][t+256] = a2A.w + r2;
      sR[4][t+256] = a2B.x + r2; sR[5][t+256] = a2B.y + r2;
      sR[6][t+256] = a2B.z + r2; sR[7][t+256] = a2B.w + r2;
    }
  }
  __syncthreads();

  // derived params per b
  for (int bb = 0; bb < BT; ++bb){
    float* pb = pws + (size_t)(bbase + bb) * WS_STRIDE;
    if (t < 64){                          // wave 0: read key
      float kt = tanhf(sR[bb][t]);
      pb[128 + t] = kt;
      float s = wave_sum(kt * kt);
      if (t == 0) pb[320] = sqrtf(s);
    } else if (t < 128){                  // wave 1: write key
      int m = t - 64;
      float kt = tanhf(sR[bb][PSZ + m]);
      pb[192 + m] = kt;
      float s = wave_sum(kt * kt);
      if (m == 0) pb[328] = sqrtf(s);
    } else if (t < 192){                  // wave 2: e, a -> a - e
      int m = t - 128;
      float e = sigmoidf_(sR[bb][2 * PSZ + m]);
      float a = tanhf(sR[bb][2 * PSZ + MM + m]);
      pb[256 + m] = a - e;
    } else if (t == 192 || t == 193){     // scalars for each head
      int off = (t == 192) ? 0 : PSZ;
      int po  = (t == 192) ? 320 : 328;
      float beta = sR[bb][off + 64];
      float g    = sR[bb][off + 65];
      float s0 = sR[bb][off + 66], s1 = sR[bb][off + 67], s2 = sR[bb][off + 68];
      float gm = sR[bb][off + 69];
      pb[po + 1] = softplusf_(beta);
      pb[po + 2] = sigmoidf_(g);
      float mx = fmaxf(s0, fmaxf(s1, s2));
      float e0 = expf(s0 - mx), e1 = expf(s1 - mx), e2 = expf(s2 - mx);
      float inv = 1.f / (e0 + e1 + e2);
      pb[po + 3] = e0 * inv; pb[po + 4] = e1 * inv; pb[po + 5] = e2 * inv;
      pb[po + 6] = softplusf_(gm) + 1.f;
    }
  }
}

// ---------------- Kernel 2: addressing + read + bank update + seq_out -----
// 512 threads, one b per block. Bank slice register-resident (16 x float4).
// Both heads addressed in ONE fused pass: no block-max (softmax uses the
// analytic bound max(beta*cos) <= beta, exact by shift invariance), dual
// block-sums share syncthreads: 5 syncs in phase B vs 16 before.
__global__ __launch_bounds__(512, 2) void k_head(
    const float* __restrict__ bank,
    const float* __restrict__ w_read, const float* __restrict__ w_write,
    const float* __restrict__ outW, const float* __restrict__ outb,
    const float* __restrict__ pws,
    float* __restrict__ out)   // [B*8 seq_out][B*N*M new_bank]
{
  __shared__ float dotr[512], dotw[512], ssv[512];
  __shared__ float tmpr[512], tmpw[512], wfr[512], wfw[512];
  __shared__ float2 red2[8];
  __shared__ float readpart[8][64];
  __shared__ float readv[64];

  const int b = blockIdx.x;
  const int t = threadIdx.x;
  const int lane = t & 63, wave = t >> 6;
  const int mg = lane & 15;        // m-group: covers m = mg*4 .. mg*4+3
  const int rsub = lane >> 4;      // row-sub within wave (0..3)

  const float* bankB = bank + (size_t)b * (NN * MM);
  const float* pb = pws + (size_t)b * WS_STRIDE;

  // prefetch prev weights + scalar params (hide latency under bank stream)
  const float wpr = w_read [(size_t)b * NN + t];
  const float wpw = w_write[(size_t)b * NN + t];
  const float knr = pb[320], br = pb[321], gr = pb[322];
  const float smr0 = pb[323], smr1 = pb[324], smr2 = pb[325], gmr = pb[326];
  const float knw = pb[328], bw = pb[329], gw = pb[330];
  const float smw0 = pb[331], smw1 = pb[332], smw2 = pb[333], gmw = pb[334];

  const float4 ktr = *(const float4*)(pb + 128 + mg * 4);
  const float4 ktw = *(const float4*)(pb + 192 + mg * 4);

  // ---- pass A: load bank slice into registers (coalesced) ----
  float4 bank_r[16];
  #pragma unroll
  for (int it = 0; it < 16; ++it){
    int n = it * 32 + wave * 4 + rsub;
    bank_r[it] = *(const float4*)(bankB + n * MM + mg * 4);
  }

  // dot products with both keys + row sum-of-squares (16-lane reduce)
  #pragma unroll
  for (int it = 0; it < 16; ++it){
    float4 p = bank_r[it];
    float dr = p.x * ktr.x + p.y * ktr.y + p.z * ktr.z + p.w * ktr.w;
    float dw = p.x * ktw.x + p.y * ktw.y + p.z * ktw.z + p.w * ktw.w;
    float sq = p.x * p.x + p.y * p.y + p.z * p.z + p.w * p.w;
    #pragma unroll
    for (int msk = 1; msk < 16; msk <<= 1){
      dr += __shfl_xor(dr, msk);
      dw += __shfl_xor(dw, msk);
      sq += __shfl_xor(sq, msk);
    }
    if (mg == 0){
      int n = it * 32 + wave * 4 + rsub;
      dotr[n] = dr; dotw[n] = dw; ssv[n] = sq;
    }
  }
  __syncthreads();

  // ---- phase B: fused dual-head addressing, thread t = memory row t ----
  {
    float rn = sqrtf(ssv[t]);
    float cr = dotr[t] / fmaxf(rn * knr, 1e-8f);
    float cw = dotw[t] / fmaxf(rn * knw, 1e-8f);
    // softmax with analytic max bound: cos <= 1 so max(beta*c) <= beta (exact)
    float er = expf(br * (cr - 1.f));
    float ew = expf(bw * (cw - 1.f));
    float sr = er, sw = ew;
    #pragma unroll
    for (int o = 32; o; o >>= 1){ sr += __shfl_xor(sr, o); sw += __shfl_xor(sw, o); }
    if (lane == 0) red2[wave] = make_float2(sr, sw);
    __syncthreads();
    float Sr = 0.f, Sw = 0.f;
    #pragma unroll
    for (int i = 0; i < 8; ++i){ Sr += red2[i].x; Sw += red2[i].y; }
    float wgr = gr * (er / Sr) + (1.f - gr) * wpr;
    float wgw = gw * (ew / Sw) + (1.f - gw) * wpw;
    tmpr[t] = wgr; tmpw[t] = wgw;
    __syncthreads();
    float wsr = tmpr[(t + 511) & 511] * smr0 + wgr * smr1 + tmpr[(t + 1) & 511] * smr2;
    float wsw = tmpw[(t + 511) & 511] * smw0 + wgw * smw1 + tmpw[(t + 1) & 511] * smw2;
    float prh = powf(wsr, gmr);
    float pwh = powf(wsw, gmw);
    float s2r = prh, s2w = pwh;
    #pragma unroll
    for (int o = 32; o; o >>= 1){ s2r += __shfl_xor(s2r, o); s2w += __shfl_xor(s2w, o); }
    if (lane == 0) red2[wave] = make_float2(s2r, s2w);
    __syncthreads();
    float S2r = 0.f, S2w = 0.f;
    #pragma unroll
    for (int i = 0; i < 8; ++i){ S2r += red2[i].x; S2w += red2[i].y; }
    wfr[t] = prh / S2r;
    wfw[t] = pwh / S2w;
    __syncthreads();
  }

  // ---- pass C: read vector + new_bank write, from registers ----
  const float4 ae4 = *(const float4*)(pb + 256 + mg * 4);
  float* outBank = out + (size_t)B_TOT * 8 + (size_t)b * (NN * MM);
  float4 racc = make_float4(0.f, 0.f, 0.f, 0.f);
  #pragma unroll
  for (int it = 0; it < 16; ++it){
    int n = it * 32 + wave * 4 + rsub;
    float4 p = bank_r[it];
    float wr = wfr[n], wwn = wfw[n];
    float4 q;
    q.x = p.x + wwn * ae4.x; q.y = p.y + wwn * ae4.y;
    q.z = p.z + wwn * ae4.z; q.w = p.w + wwn * ae4.w;
    *(float4*)(outBank + n * MM + mg * 4) = q;
    racc.x += wr * p.x; racc.y += wr * p.y; racc.z += wr * p.z; racc.w += wr * p.w;
  }
  // reduce read accumulator over rows (lanes sharing mg differ in bits 4,5)
  racc.x += __shfl_xor(racc.x, 16); racc.x += __shfl_xor(racc.x, 32);
  racc.y += __shfl_xor(racc.y, 16); racc.y += __shfl_xor(racc.y, 32);
  racc.z += __shfl_xor(racc.z, 16); racc.z += __shfl_xor(racc.z, 32);
  racc.w += __shfl_xor(racc.w, 16); racc.w += __shfl_xor(racc.w, 32);
  if (lane < 16){
    readpart[wave][mg * 4 + 0] = racc.x;
    readpart[wave][mg * 4 + 1] = racc.y;
    readpart[wave][mg * 4 + 2] = racc.z;
    readpart[wave][mg * 4 + 3] = racc.w;
  }
  __syncthreads();
  if (t < 64){
    float s = 0.f;
    #pragma unroll
    for (int w = 0; w < 8; ++w) s += readpart[w][t];
    readv[t] = s;
  }
  __syncthreads();

  // ---- seq_out: sigmoid([ctrl_out, read] @ outW + outb), wave-parallel ----
  if (t < 64){
    int j = t >> 3, s = t & 7;       // output j, partial-slice s
    float acc = 0.f;
    for (int i = s; i < COUT; i += 8) acc += pb[i] * outW[i * 8 + j];
    for (int m = s; m < MM; m += 8)   acc += readv[m] * outW[(COUT + m) * 8 + j];
    acc += __shfl_xor(acc, 1);
    acc += __shfl_xor(acc, 2);
    acc += __shfl_xor(acc, 4);
    if (s == 0) out[(size_t)b * 8 + j] = sigmoidf_(acc + outb[j]);
  }
}

extern "C" void kernel_launch(void* const* d_in, const int* in_sizes, int n_in,
                              void* d_out, int out_size, void* d_ws, size_t ws_size,
                              hipStream_t stream) {
  const float* x         = (const float*)d_in[0];
  const float* prev_read = (const float*)d_in[1];
  const float* bank      = (const float*)d_in[2];
  const float* w_read    = (const float*)d_in[3];
  const float* w_write   = (const float*)d_in[4];
  const float* W0        = (const float*)d_in[5];
  const float* b0        = (const float*)d_in[6];
  const float* W1        = (const float*)d_in[7];
  const float* b1        = (const float*)d_in[8];
  const float* Wout      = (const float*)d_in[9];
  const float* bout      = (const float*)d_in[10];
  const float* rW        = (const float*)d_in[11];
  const float* rb        = (const float*)d_in[12];
  const float* outW      = (const float*)d_in[13];
  const float* outb      = (const float*)d_in[14];
  float* out = (float*)d_out;
  float* pws = (float*)d_ws;   // needs 4096*352*4 = 5.77 MB

  k_ctrl<<<dim3(B_TOT / BT), dim3(256), 0, stream>>>(
      x, prev_read, W0, b0, W1, b1, Wout, bout, rW, rb, pws);
  k_head<<<dim3(B_TOT), dim3(512), 0, stream>>>(
      bank, w_read, w_write, outW, outb, pws, out);
}